// Round 7
// baseline (1789.331 us; speedup 1.0000x reference)
//
#include <hip/hip_runtime.h>
#include <hip/hip_bf16.h>
#include <cstdint>
#include <cstddef>

// Problem constants (from reference)
#define NPTS  1000000
#define BSEG  2000
#define DIN   16
#define HDIM  256
#define DOUT  128
#define NTILE (NPTS / 32)   // 31250 tiles of 32 points
#define NWG   1024          // persistent workgroups (4/CU; 128 VGPR x 4 waves/SIMD = full file)

typedef __bf16          bf16x8 __attribute__((ext_vector_type(8)));
typedef unsigned short  us16x8 __attribute__((ext_vector_type(8)));
typedef unsigned int    u32x4  __attribute__((ext_vector_type(4)));
typedef float           f32x4  __attribute__((ext_vector_type(4)));
typedef float           f32x2  __attribute__((ext_vector_type(2)));

static __device__ __forceinline__ unsigned short f2bf(float x) {
    unsigned int u = __float_as_uint(x);
    u += 0x7fffu + ((u >> 16) & 1u);
    return (unsigned short)(u >> 16);
}

static __device__ __forceinline__ bf16x8 ldb8(const unsigned short* p) {
    u32x4 v = *(const u32x4*)p;
    return __builtin_bit_cast(bf16x8, v);
}
static __device__ __forceinline__ f32x4 mfma16(bf16x8 a, bf16x8 b, f32x4 c) {
    return __builtin_amdgcn_mfma_f32_16x16x32_bf16(a, b, c, 0, 0, 0);
}
static __device__ __forceinline__ void keep(bf16x8& v) {
    u32x4 u = __builtin_bit_cast(u32x4, v);
    unsigned a0 = u[0], a1 = u[1], a2 = u[2], a3 = u[3];
    asm volatile("" : "+v"(a0), "+v"(a1), "+v"(a2), "+v"(a3));
    u32x4 r; r[0] = a0; r[1] = a1; r[2] = a2; r[3] = a3;
    v = __builtin_bit_cast(bf16x8, r);
}

// ---- packed-f32 VALU helpers (no v_pk_max_f32 on gfx950: ReLU is scalar) ----
static __device__ __forceinline__ f32x2 pkadd(f32x2 a, f32x2 b) {
    f32x2 d; asm("v_pk_add_f32 %0, %1, %2" : "=v"(d) : "v"(a), "v"(b)); return d;
}
static __device__ __forceinline__ f32x2 pkmul(f32x2 a, f32x2 b) {
    f32x2 d; asm("v_pk_mul_f32 %0, %1, %2" : "=v"(d) : "v"(a), "v"(b)); return d;
}
static __device__ __forceinline__ f32x2 pkfma(f32x2 a, f32x2 b, f32x2 c) {
    f32x2 d; asm("v_pk_fma_f32 %0, %1, %2, %3" : "=v"(d) : "v"(a), "v"(b), "v"(c)); return d;
}
static __device__ __forceinline__ f32x2 relu2(f32x2 a) {
    f32x2 d; d[0] = fmaxf(a[0], 0.f); d[1] = fmaxf(a[1], 0.f); return d;
}
static __device__ __forceinline__ unsigned cvtpk(float a, float b) {
    unsigned d; asm("v_cvt_pk_bf16_f32 %0, %1, %2" : "=v"(d) : "v"(a), "v"(b)); return d;
}
static __device__ __forceinline__ f32x2 lohalf(f32x4 v) { return __builtin_shufflevector(v, v, 0, 1); }
static __device__ __forceinline__ f32x2 hihalf(f32x4 v) { return __builtin_shufflevector(v, v, 2, 3); }

// Sum across the 16 lanes of a DPP row using row_ror 8/4/2/1.
static __device__ __forceinline__ float rsum16(float x) {
    x += __builtin_bit_cast(float, __builtin_amdgcn_update_dpp(
             0, __builtin_bit_cast(int, x), 0x128, 0xf, 0xf, false)); // ror:8
    x += __builtin_bit_cast(float, __builtin_amdgcn_update_dpp(
             0, __builtin_bit_cast(int, x), 0x124, 0xf, 0xf, false)); // ror:4
    x += __builtin_bit_cast(float, __builtin_amdgcn_update_dpp(
             0, __builtin_bit_cast(int, x), 0x122, 0xf, 0xf, false)); // ror:2
    x += __builtin_bit_cast(float, __builtin_amdgcn_update_dpp(
             0, __builtin_bit_cast(int, x), 0x121, 0xf, 0xf, false)); // ror:1
    return x;
}

// ---------------------------------------------------------------------------
__global__ __launch_bounds__(1024) void scan_counts(const int* __restrict__ counts,
                                                    int* __restrict__ offsets) {
    __shared__ int a[2048];
    const int t = threadIdx.x;
    a[t]        = (t        < BSEG) ? counts[t]        : 0;
    a[t + 1024] = (t + 1024 < BSEG) ? counts[t + 1024] : 0;
    for (int s = 1; s < 2048; s <<= 1) {
        __syncthreads();
        int x1 = (t >= s) ? a[t - s] : 0;
        int x2 = a[t + 1024 - s];
        __syncthreads();
        a[t] += x1;
        a[t + 1024] += x2;
    }
    __syncthreads();
    if (t == 0) offsets[0] = 0;
    offsets[t + 1] = a[t];
    if (t + 1024 < BSEG) offsets[t + 1025] = a[t + 1024];
}

__global__ __launch_bounds__(256) void fill_seg(const int* __restrict__ offsets,
                                                unsigned short* __restrict__ seg) {
    const int b  = blockIdx.x;
    const int lo = offsets[b], hi = offsets[b + 1];
    for (int i = lo + threadIdx.x; i < hi; i += 256) seg[i] = (unsigned short)b;
}

// W1T [256][32] (K zero-padded 16->32, bias folded into k==16 row, paired with
// A[k=16]=1.0 in the fused kernel), W2T [256][256]; [n][k]-major bf16.
__global__ __launch_bounds__(256) void prep_weights(const float* __restrict__ W1,
                                                    const float* __restrict__ b1,
                                                    const float* __restrict__ W2,
                                                    unsigned short* __restrict__ w1t,
                                                    unsigned short* __restrict__ w2t) {
    const int i = blockIdx.x * 256 + threadIdx.x;
    if (i < HDIM * 32) {
        int n = i >> 5, k = i & 31;
        float v = (k < DIN) ? W1[k * HDIM + n] : ((k == DIN) ? b1[n] : 0.f);
        w1t[i] = f2bf(v);
    } else {
        int j = i - HDIM * 32;
        if (j < HDIM * HDIM) {
            int n = j >> 8, k = j & 255;
            w2t[j] = f2bf(W2[k * HDIM + n]);
        }
    }
}

// ---------------------------------------------------------------------------
// Persistent fused kernel (round-2 structure): strided tile walk, per-tile
// shfl+atomic pooling. Tile M=32 points, 4 waves; wave w owns cols
// [w*64, w*64+64). W2 register-resident; W1 in LDS; LN stats via DPP row_ror
// with packed-f32 row-pair math; z software-pipelined one tile ahead.
// NWG=1024 / launch_bounds(256,4): 4 blocks/CU (128 VGPR x 4 waves/SIMD = 512
// = full file; LDS 4 x 36.3 KB = 145 KB < 160 KB) -> TLP hides barrier drains.
// ---------------------------------------------------------------------------
__global__ __launch_bounds__(256, 4) void fused_phi_pool(
    const float* __restrict__ z,
    const unsigned short* __restrict__ w1t,
    const unsigned short* __restrict__ w2t,
    const float* __restrict__ g1, const float* __restrict__ be1,
    const float* __restrict__ b2, const float* __restrict__ g2, const float* __restrict__ be2,
    const unsigned short* __restrict__ seg,
    float* __restrict__ sums_h) {
    __shared__ __align__(16) unsigned short h1[32][264];     // 16896 B
    __shared__ __align__(16) unsigned short w1l[HDIM * 32];  // 16384 B
    __shared__ __align__(16) float part2[2][2][8][20];       //  2560 B
    __shared__ int seg_sm[2][32];

    const int tid  = threadIdx.x;
    const int wave = tid >> 6;
    const int lane = tid & 63;
    const int l15  = lane & 15;
    const int quad = lane >> 4;
    const int colw = wave * 64 + l15;
    const bool zlane = (quad < 2);   // only k<16 lanes carry layer-1 A data

    // ---- one-time: stage W1^T (incl. bias row) into LDS ----
    {
        const u32x4* src = (const u32x4*)w1t;
        u32x4* dst = (u32x4*)w1l;
        for (int i = tid; i < HDIM * 32 / 8; i += 256) dst[i] = src[i];
    }

    // ---- one-time: register-resident W2 fragments ----
    bf16x8 bw2[4][8];
#pragma unroll
    for (int t = 0; t < 4; ++t) {
        const int n = (wave * 4 + t) * 16 + l15;
#pragma unroll
        for (int ks = 0; ks < 8; ++ks) {
            bw2[t][ks] = ldb8(w2t + n * 256 + ks * 32 + quad * 8);
            keep(bw2[t][ks]);
        }
    }

    // ---- duplicated-pair LN coefficients (for packed math) ----
    f32x2 gd1[4], ed1[4], gd2[4], ed2[4], bd2[4];
#pragma unroll
    for (int t = 0; t < 4; ++t) {
        const int c = colw + t * 16;
        float gv = g1[c];  gd1[t][0] = gv; gd1[t][1] = gv;
        float ev = be1[c]; ed1[t][0] = ev; ed1[t][1] = ev;
        float g2v = g2[c]; gd2[t][0] = g2v; gd2[t][1] = g2v;
        float e2v = be2[c]; ed2[t][0] = e2v; ed2[t][1] = e2v;
        float b2v = b2[c]; bd2[t][0] = b2v; bd2[t][1] = b2v;
    }
    const f32x2 zero2 = {0.f, 0.f};
    const unsigned h1w = (unsigned)(size_t)&h1[quad * 4][colw];

    // ---- z prefetch pipeline (one tile ahead, registers only) ----
    float4 zn[2][2];   // [mb][half] raw fp32, valid on zlane only
    {
        const int base0 = blockIdx.x * 32;
        if (zlane) {
#pragma unroll
            for (int mb = 0; mb < 2; ++mb) {
                const float* zp = z + (size_t)(base0 + mb * 16 + l15) * DIN + quad * 8;
                zn[mb][0] = *(const float4*)zp;
                zn[mb][1] = *(const float4*)(zp + 4);
            }
        }
    }

    __syncthreads();   // w1l visible to all waves

    int p = 0;
    for (int tile = blockIdx.x; tile < NTILE; tile += NWG, p ^= 1) {
        const int base = tile * 32;
        if (tid < 32) seg_sm[p][tid] = (int)seg[base + tid];

        float4 zc[2][2];
#pragma unroll
        for (int mb = 0; mb < 2; ++mb) { zc[mb][0] = zn[mb][0]; zc[mb][1] = zn[mb][1]; }
        const int ntile = tile + NWG;
        if (zlane && ntile < NTILE) {
            const int nb = ntile * 32;
#pragma unroll
            for (int mb = 0; mb < 2; ++mb) {
                const float* zp = z + (size_t)(nb + mb * 16 + l15) * DIN + quad * 8;
                zn[mb][0] = *(const float4*)zp;
                zn[mb][1] = *(const float4*)(zp + 4);
            }
        }

        // ---------------- layer 1 (K=16 padded to 32; bias in k=16 lane) ----
        bf16x8 w1f[4];
#pragma unroll
        for (int t = 0; t < 4; ++t)
            w1f[t] = ldb8(&w1l[((wave * 4 + t) * 16 + l15) * 32 + quad * 8]);

        f32x4 a1[2][4];
#pragma unroll
        for (int mb = 0; mb < 2; ++mb) {
            bf16x8 af;
            if (zlane) {
                u32x4 u;
                u[0] = cvtpk(zc[mb][0].x, zc[mb][0].y);
                u[1] = cvtpk(zc[mb][0].z, zc[mb][0].w);
                u[2] = cvtpk(zc[mb][1].x, zc[mb][1].y);
                u[3] = cvtpk(zc[mb][1].z, zc[mb][1].w);
                af = __builtin_bit_cast(bf16x8, u);
            } else {
                u32x4 u = {(quad == 2) ? 0x3F80u : 0u, 0u, 0u, 0u};   // bias lane
                af = __builtin_bit_cast(bf16x8, u);
            }
            const f32x4 zero = {0.f, 0.f, 0.f, 0.f};
#pragma unroll
            for (int t = 0; t < 4; ++t) a1[mb][t] = mfma16(af, w1f[t], zero);
        }

        // LN1 stats (row-pair packed; bias inside MFMA)
#pragma unroll
        for (int mb = 0; mb < 2; ++mb)
#pragma unroll
            for (int rp = 0; rp < 2; ++rp) {
                f32x2 sv = zero2, qv = zero2;
#pragma unroll
                for (int t = 0; t < 4; ++t) {
                    f32x2 y = rp ? hihalf(a1[mb][t]) : lohalf(a1[mb][t]);
                    sv = pkadd(sv, y);
                    qv = pkfma(y, y, qv);
                }
                float sa = rsum16(sv[0]), sb = rsum16(sv[1]);
                float qa = rsum16(qv[0]), qb = rsum16(qv[1]);
                if (l15 == 0) {
                    f32x2 s2 = {sa, sb};
                    f32x2 q2 = {qa, qb};
                    *(f32x2*)&part2[p][mb][quad * 2 + rp][wave * 2]     = s2;
                    *(f32x2*)&part2[p][mb][quad * 2 + rp][8 + wave * 2] = q2;
                }
            }
        __syncthreads();   // B1: stats visible; prior-iter h1 readers done

        // LN1 apply + ReLU + bf16 store (packed cvt + paired b16/b16_hi stores)
#pragma unroll
        for (int mb = 0; mb < 2; ++mb)
#pragma unroll
            for (int rp = 0; rp < 2; ++rp) {
                const float* pr = &part2[p][mb][quad * 2 + rp][0];
                f32x4 sa4 = *(const f32x4*)pr;
                f32x4 sb4 = *(const f32x4*)(pr + 4);
                f32x4 qa4 = *(const f32x4*)(pr + 8);
                f32x4 qb4 = *(const f32x4*)(pr + 12);
                f32x2 st2 = pkadd(pkadd(lohalf(sa4), hihalf(sa4)),
                                  pkadd(lohalf(sb4), hihalf(sb4)));
                f32x2 qt2 = pkadd(pkadd(lohalf(qa4), hihalf(qa4)),
                                  pkadd(lohalf(qb4), hihalf(qb4)));
                float m0 = st2[0] * (1.f / 256.f), m1 = st2[1] * (1.f / 256.f);
                float v0 = fmaf(qt2[0], 1.f / 256.f, -(m0 * m0));
                float v1 = fmaf(qt2[1], 1.f / 256.f, -(m1 * m1));
                float r0 = rsqrtf(fmaxf(v0, 0.f) + 1e-5f);
                float r1 = rsqrtf(fmaxf(v1, 0.f) + 1e-5f);
                f32x2 rs2 = {r0, r1};
                f32x2 mn2 = {-m0, -m1};
#pragma unroll
                for (int t = 0; t < 4; ++t) {
                    f32x2 A2 = pkmul(rs2, gd1[t]);
                    f32x2 C2 = pkfma(mn2, A2, ed1[t]);
                    f32x2 y  = rp ? hihalf(a1[mb][t]) : lohalf(a1[mb][t]);
                    f32x2 h2 = relu2(pkfma(y, A2, C2));
                    unsigned pkv  = cvtpk(h2[0], h2[1]);
                    unsigned addr = h1w + (unsigned)(mb * 8448 + rp * 1056 + t * 32);
                    asm volatile("ds_write_b16 %0, %1\n\t"
                                 "ds_write_b16_d16_hi %0, %1 offset:528"
                                 :: "v"(addr), "v"(pkv));
                }
            }
        __syncthreads();   // B2: h1 ready

        // ---------------- layer 2 ----------------
        f32x4 a2[2][4];
#pragma unroll
        for (int mb = 0; mb < 2; ++mb) {
            const f32x4 zero = {0.f, 0.f, 0.f, 0.f};
#pragma unroll
            for (int t = 0; t < 4; ++t) a2[mb][t] = zero;
#pragma unroll
            for (int ks = 0; ks < 8; ++ks) {
                bf16x8 af = ldb8(&h1[mb * 16 + l15][ks * 32 + quad * 8]);
#pragma unroll
                for (int t = 0; t < 4; ++t) a2[mb][t] = mfma16(af, bw2[t][ks], a2[mb][t]);
            }
        }
        // LN2 stats (y = a2 + b2, packed)
#pragma unroll
        for (int mb = 0; mb < 2; ++mb)
#pragma unroll
            for (int rp = 0; rp < 2; ++rp) {
                f32x2 sv = zero2, qv = zero2;
#pragma unroll
                for (int t = 0; t < 4; ++t) {
                    f32x2 y = pkadd(rp ? hihalf(a2[mb][t]) : lohalf(a2[mb][t]), bd2[t]);
                    sv = pkadd(sv, y);
                    qv = pkfma(y, y, qv);
                }
                float sa = rsum16(sv[0]), sb = rsum16(sv[1]);
                float qa = rsum16(qv[0]), qb = rsum16(qv[1]);
                if (l15 == 0) {
                    f32x2 s2 = {sa, sb};
                    f32x2 q2 = {qa, qb};
                    *(f32x2*)&part2[p][mb][quad * 2 + rp][wave * 2]     = s2;
                    *(f32x2*)&part2[p][mb][quad * 2 + rp][8 + wave * 2] = q2;
                }
            }
        __syncthreads();   // B3: layer-2 stats visible

        // LN2 apply + ReLU, written back into a2 for pooling
#pragma unroll
        for (int mb = 0; mb < 2; ++mb)
#pragma unroll
            for (int rp = 0; rp < 2; ++rp) {
                const float* pr = &part2[p][mb][quad * 2 + rp][0];
                f32x4 sa4 = *(const f32x4*)pr;
                f32x4 sb4 = *(const f32x4*)(pr + 4);
                f32x4 qa4 = *(const f32x4*)(pr + 8);
                f32x4 qb4 = *(const f32x4*)(pr + 12);
                f32x2 st2 = pkadd(pkadd(lohalf(sa4), hihalf(sa4)),
                                  pkadd(lohalf(sb4), hihalf(sb4)));
                f32x2 qt2 = pkadd(pkadd(lohalf(qa4), hihalf(qa4)),
                                  pkadd(lohalf(qb4), hihalf(qb4)));
                float m0 = st2[0] * (1.f / 256.f), m1 = st2[1] * (1.f / 256.f);
                float v0 = fmaf(qt2[0], 1.f / 256.f, -(m0 * m0));
                float v1 = fmaf(qt2[1], 1.f / 256.f, -(m1 * m1));
                float r0 = rsqrtf(fmaxf(v0, 0.f) + 1e-5f);
                float r1 = rsqrtf(fmaxf(v1, 0.f) + 1e-5f);
                f32x2 rs2 = {r0, r1};
                f32x2 mn2 = {-m0, -m1};
#pragma unroll
                for (int t = 0; t < 4; ++t) {
                    f32x2 A2 = pkmul(rs2, gd2[t]);
                    f32x2 C2 = pkfma(mn2, A2, ed2[t]);
                    f32x2 y  = pkadd(rp ? hihalf(a2[mb][t]) : lohalf(a2[mb][t]), bd2[t]);
                    f32x2 h2 = relu2(pkfma(y, A2, C2));
                    a2[mb][t][rp * 2]     = h2[0];
                    a2[mb][t][rp * 2 + 1] = h2[1];
                }
            }

        // ---------------- ragged segment-sum of h2 (fp32) ----------------
        const int s0  = seg_sm[p][0];
        const int s31 = seg_sm[p][31];
        if (s0 == s31) {   // tile entirely inside one segment (~94%)
#pragma unroll
            for (int t = 0; t < 4; ++t) {
                float cs = a2[0][t][0] + a2[0][t][1] + a2[0][t][2] + a2[0][t][3]
                         + a2[1][t][0] + a2[1][t][1] + a2[1][t][2] + a2[1][t][3];
                cs += __shfl_xor(cs, 16, 64);
                cs += __shfl_xor(cs, 32, 64);
                if (quad == 0)
                    atomicAdd(&sums_h[s0 * HDIM + colw + t * 16], cs);
            }
        } else {           // exactly 2 segments (min count 100 > 32)
            const int* sgp = &seg_sm[p][0];
            float m0v[4], m1v[4];
#pragma unroll
            for (int r = 0; r < 4; ++r) {
                m0v[r] = (sgp[quad * 4 + r]      == s0) ? 1.f : 0.f;
                m1v[r] = (sgp[16 + quad * 4 + r] == s0) ? 1.f : 0.f;
            }
#pragma unroll
            for (int t = 0; t < 4; ++t) {
                float cs = 0.f, ca = 0.f;
#pragma unroll
                for (int r = 0; r < 4; ++r) {
                    cs += a2[0][t][r] + a2[1][t][r];
                    ca = fmaf(a2[0][t][r], m0v[r], ca);
                    ca = fmaf(a2[1][t][r], m1v[r], ca);
                }
                cs += __shfl_xor(cs, 16, 64);
                cs += __shfl_xor(cs, 32, 64);
                ca += __shfl_xor(ca, 16, 64);
                ca += __shfl_xor(ca, 32, 64);
                if (quad == 0) {
                    atomicAdd(&sums_h[s0  * HDIM + colw + t * 16], ca);
                    atomicAdd(&sums_h[s31 * HDIM + colw + t * 16], cs - ca);
                }
            }
        }
    }
}

// ---------------------------------------------------------------------------
// emb[b] = (sums_h[b] @ W3) / count_b + b3
// One segment per block: sh[k] addresses are block-uniform -> scalar (SMEM)
// loads; W3 row reads are coalesced across the 128 threads.
// ---------------------------------------------------------------------------
__global__ __launch_bounds__(128) void emb_gemm(const float* __restrict__ sums_h,
                                                const float* __restrict__ W3,
                                                const float* __restrict__ b3,
                                                const int* __restrict__ counts,
                                                float* __restrict__ emb) {
    const int b = blockIdx.x;
    const int o = threadIdx.x;
    const float* sh = sums_h + b * HDIM;
    float acc = 0.f;
#pragma unroll 8
    for (int k = 0; k < HDIM; ++k) acc = fmaf(sh[k], W3[k * DOUT + o], acc);
    emb[b * DOUT + o] = acc / (float)counts[b] + b3[o];
}

// ---------------------------------------------------------------------------
// out[n] = emb[seg[n]] ; unit-stride float4 per thread, nontemporal stores
// (round-2 proven gather version: perfectly balanced 125k blocks)
// ---------------------------------------------------------------------------
__global__ __launch_bounds__(256) void broadcast_out(const float* __restrict__ emb,
                                                     const unsigned short* __restrict__ seg,
                                                     float* __restrict__ out) {
    const int idx = blockIdx.x * 256 + threadIdx.x;   // one float4; N*DOUT/4 total
    const int n = idx >> 5, c = idx & 31;
    const int s = seg[n];
    f32x4 v = ((const f32x4*)emb)[s * 32 + c];
    __builtin_nontemporal_store(v, (f32x4*)out + idx);
}

// ---------------------------------------------------------------------------
extern "C" void kernel_launch(void* const* d_in, const int* in_sizes, int n_in,
                              void* d_out, int out_size, void* d_ws, size_t ws_size,
                              hipStream_t stream) {
    const float* z   = (const float*)d_in[0];
    const float* W1  = (const float*)d_in[1];
    const float* b1  = (const float*)d_in[2];
    const float* g1  = (const float*)d_in[3];
    const float* be1 = (const float*)d_in[4];
    const float* W2  = (const float*)d_in[5];
    const float* b2  = (const float*)d_in[6];
    const float* g2  = (const float*)d_in[7];
    const float* be2 = (const float*)d_in[8];
    const float* W3  = (const float*)d_in[9];
    const float* b3  = (const float*)d_in[10];
    const int* counts = (const int*)d_in[11];
    float* out = (float*)d_out;

    char* ws = (char*)d_ws;
    float*          sums_h  = (float*)(ws);                     // 2,048,000 B
    float*          emb     = (float*)(ws + 2048000);           // 1,024,000 B
    int*            offsets = (int*)  (ws + 3072000);           //     8,016 B
    unsigned short* seg     = (unsigned short*)(ws + 3080016);  // 2,000,000 B
    unsigned short* w1t     = (unsigned short*)(ws + 5080016);  //    16,384 B
    unsigned short* w2t     = (unsigned short*)(ws + 5096400);  //   131,072 B

    hipMemsetAsync(sums_h, 0, (size_t)BSEG * HDIM * sizeof(float), stream);
    scan_counts<<<1, 1024, 0, stream>>>(counts, offsets);
    fill_seg<<<BSEG, 256, 0, stream>>>(offsets, seg);
    prep_weights<<<(HDIM * 32 + HDIM * HDIM) / 256, 256, 0, stream>>>(W1, b1, W2, w1t, w2t);
    fused_phi_pool<<<NWG, 256, 0, stream>>>(z, w1t, w2t,
                                            g1, be1, b2, g2, be2,
                                            seg, sums_h);
    emb_gemm<<<BSEG, 128, 0, stream>>>(sums_h, W3, b3, counts, emb);
    broadcast_out<<<NPTS * DOUT / 4 / 256, 256, 0, stream>>>(emb, seg, out);
}

// Round 8
// 934.153 us; speedup vs baseline: 1.9155x; 1.9155x over previous
//
#include <hip/hip_runtime.h>
#include <hip/hip_bf16.h>
#include <cstdint>
#include <cstddef>

// Problem constants (from reference)
#define NPTS  1000000
#define BSEG  2000
#define DIN   16
#define HDIM  256
#define DOUT  128
#define NTILE (NPTS / 32)   // 31250 tiles of 32 points
#define NWG   1024          // grid oversubscribed; residency decided by HW resources
                            // NOTE: launch_bounds stays (256,2) — raising the min-waves
                            // arg re-budgets the allocator and spills W2 (round-7: 3.7GB
                            // of scratch traffic, 434->1230us). Grid size alone is safe.

typedef __bf16          bf16x8 __attribute__((ext_vector_type(8)));
typedef unsigned short  us16x8 __attribute__((ext_vector_type(8)));
typedef unsigned int    u32x4  __attribute__((ext_vector_type(4)));
typedef float           f32x4  __attribute__((ext_vector_type(4)));
typedef float           f32x2  __attribute__((ext_vector_type(2)));

static __device__ __forceinline__ unsigned short f2bf(float x) {
    unsigned int u = __float_as_uint(x);
    u += 0x7fffu + ((u >> 16) & 1u);
    return (unsigned short)(u >> 16);
}

static __device__ __forceinline__ bf16x8 ldb8(const unsigned short* p) {
    u32x4 v = *(const u32x4*)p;
    return __builtin_bit_cast(bf16x8, v);
}
static __device__ __forceinline__ f32x4 mfma16(bf16x8 a, bf16x8 b, f32x4 c) {
    return __builtin_amdgcn_mfma_f32_16x16x32_bf16(a, b, c, 0, 0, 0);
}
static __device__ __forceinline__ void keep(bf16x8& v) {
    u32x4 u = __builtin_bit_cast(u32x4, v);
    unsigned a0 = u[0], a1 = u[1], a2 = u[2], a3 = u[3];
    asm volatile("" : "+v"(a0), "+v"(a1), "+v"(a2), "+v"(a3));
    u32x4 r; r[0] = a0; r[1] = a1; r[2] = a2; r[3] = a3;
    v = __builtin_bit_cast(bf16x8, r);
}

// ---- packed-f32 VALU helpers (no v_pk_max_f32 on gfx950: ReLU is scalar) ----
static __device__ __forceinline__ f32x2 pkadd(f32x2 a, f32x2 b) {
    f32x2 d; asm("v_pk_add_f32 %0, %1, %2" : "=v"(d) : "v"(a), "v"(b)); return d;
}
static __device__ __forceinline__ f32x2 pkmul(f32x2 a, f32x2 b) {
    f32x2 d; asm("v_pk_mul_f32 %0, %1, %2" : "=v"(d) : "v"(a), "v"(b)); return d;
}
static __device__ __forceinline__ f32x2 pkfma(f32x2 a, f32x2 b, f32x2 c) {
    f32x2 d; asm("v_pk_fma_f32 %0, %1, %2, %3" : "=v"(d) : "v"(a), "v"(b), "v"(c)); return d;
}
static __device__ __forceinline__ f32x2 relu2(f32x2 a) {
    f32x2 d; d[0] = fmaxf(a[0], 0.f); d[1] = fmaxf(a[1], 0.f); return d;
}
static __device__ __forceinline__ unsigned cvtpk(float a, float b) {
    unsigned d; asm("v_cvt_pk_bf16_f32 %0, %1, %2" : "=v"(d) : "v"(a), "v"(b)); return d;
}
static __device__ __forceinline__ f32x2 lohalf(f32x4 v) { return __builtin_shufflevector(v, v, 0, 1); }
static __device__ __forceinline__ f32x2 hihalf(f32x4 v) { return __builtin_shufflevector(v, v, 2, 3); }

// Sum across the 16 lanes of a DPP row using row_ror 8/4/2/1.
static __device__ __forceinline__ float rsum16(float x) {
    x += __builtin_bit_cast(float, __builtin_amdgcn_update_dpp(
             0, __builtin_bit_cast(int, x), 0x128, 0xf, 0xf, false)); // ror:8
    x += __builtin_bit_cast(float, __builtin_amdgcn_update_dpp(
             0, __builtin_bit_cast(int, x), 0x124, 0xf, 0xf, false)); // ror:4
    x += __builtin_bit_cast(float, __builtin_amdgcn_update_dpp(
             0, __builtin_bit_cast(int, x), 0x122, 0xf, 0xf, false)); // ror:2
    x += __builtin_bit_cast(float, __builtin_amdgcn_update_dpp(
             0, __builtin_bit_cast(int, x), 0x121, 0xf, 0xf, false)); // ror:1
    return x;
}

// ---------------------------------------------------------------------------
__global__ __launch_bounds__(1024) void scan_counts(const int* __restrict__ counts,
                                                    int* __restrict__ offsets) {
    __shared__ int a[2048];
    const int t = threadIdx.x;
    a[t]        = (t        < BSEG) ? counts[t]        : 0;
    a[t + 1024] = (t + 1024 < BSEG) ? counts[t + 1024] : 0;
    for (int s = 1; s < 2048; s <<= 1) {
        __syncthreads();
        int x1 = (t >= s) ? a[t - s] : 0;
        int x2 = a[t + 1024 - s];
        __syncthreads();
        a[t] += x1;
        a[t + 1024] += x2;
    }
    __syncthreads();
    if (t == 0) offsets[0] = 0;
    offsets[t + 1] = a[t];
    if (t + 1024 < BSEG) offsets[t + 1025] = a[t + 1024];
}

__global__ __launch_bounds__(256) void fill_seg(const int* __restrict__ offsets,
                                                unsigned short* __restrict__ seg) {
    const int b  = blockIdx.x;
    const int lo = offsets[b], hi = offsets[b + 1];
    for (int i = lo + threadIdx.x; i < hi; i += 256) seg[i] = (unsigned short)b;
}

// W1T [256][32] (K zero-padded 16->32, bias folded into k==16 row, paired with
// A[k=16]=1.0 in the fused kernel), W2T [256][256]; [n][k]-major bf16.
__global__ __launch_bounds__(256) void prep_weights(const float* __restrict__ W1,
                                                    const float* __restrict__ b1,
                                                    const float* __restrict__ W2,
                                                    unsigned short* __restrict__ w1t,
                                                    unsigned short* __restrict__ w2t) {
    const int i = blockIdx.x * 256 + threadIdx.x;
    if (i < HDIM * 32) {
        int n = i >> 5, k = i & 31;
        float v = (k < DIN) ? W1[k * HDIM + n] : ((k == DIN) ? b1[n] : 0.f);
        w1t[i] = f2bf(v);
    } else {
        int j = i - HDIM * 32;
        if (j < HDIM * HDIM) {
            int n = j >> 8, k = j & 255;
            w2t[j] = f2bf(W2[k * HDIM + n]);
        }
    }
}

// ---------------------------------------------------------------------------
// Persistent fused kernel (round-2 structure, 434 us codegen): strided tile
// walk, per-tile shfl+atomic pooling. Tile M=32 points, 4 waves; wave w owns
// cols [w*64, w*64+64). W2 register-resident; W1 in LDS; LN stats via DPP
// row_ror with packed-f32 row-pair math; z software-pipelined one tile ahead.
// launch_bounds(256,2) preserved (same 128-VGPR allocation); grid oversubscribed
// to 1024 so HW can raise residency if actual registers permit.
// ---------------------------------------------------------------------------
__global__ __launch_bounds__(256, 2) void fused_phi_pool(
    const float* __restrict__ z,
    const unsigned short* __restrict__ w1t,
    const unsigned short* __restrict__ w2t,
    const float* __restrict__ g1, const float* __restrict__ be1,
    const float* __restrict__ b2, const float* __restrict__ g2, const float* __restrict__ be2,
    const unsigned short* __restrict__ seg,
    float* __restrict__ sums_h) {
    __shared__ __align__(16) unsigned short h1[32][264];     // 16896 B
    __shared__ __align__(16) unsigned short w1l[HDIM * 32];  // 16384 B
    __shared__ __align__(16) float part2[2][2][8][20];       //  2560 B
    __shared__ int seg_sm[2][32];

    const int tid  = threadIdx.x;
    const int wave = tid >> 6;
    const int lane = tid & 63;
    const int l15  = lane & 15;
    const int quad = lane >> 4;
    const int colw = wave * 64 + l15;
    const bool zlane = (quad < 2);   // only k<16 lanes carry layer-1 A data

    // ---- one-time: stage W1^T (incl. bias row) into LDS ----
    {
        const u32x4* src = (const u32x4*)w1t;
        u32x4* dst = (u32x4*)w1l;
        for (int i = tid; i < HDIM * 32 / 8; i += 256) dst[i] = src[i];
    }

    // ---- one-time: register-resident W2 fragments ----
    bf16x8 bw2[4][8];
#pragma unroll
    for (int t = 0; t < 4; ++t) {
        const int n = (wave * 4 + t) * 16 + l15;
#pragma unroll
        for (int ks = 0; ks < 8; ++ks) {
            bw2[t][ks] = ldb8(w2t + n * 256 + ks * 32 + quad * 8);
            keep(bw2[t][ks]);
        }
    }

    // ---- duplicated-pair LN coefficients (for packed math) ----
    f32x2 gd1[4], ed1[4], gd2[4], ed2[4], bd2[4];
#pragma unroll
    for (int t = 0; t < 4; ++t) {
        const int c = colw + t * 16;
        float gv = g1[c];  gd1[t][0] = gv; gd1[t][1] = gv;
        float ev = be1[c]; ed1[t][0] = ev; ed1[t][1] = ev;
        float g2v = g2[c]; gd2[t][0] = g2v; gd2[t][1] = g2v;
        float e2v = be2[c]; ed2[t][0] = e2v; ed2[t][1] = e2v;
        float b2v = b2[c]; bd2[t][0] = b2v; bd2[t][1] = b2v;
    }
    const f32x2 zero2 = {0.f, 0.f};
    const unsigned h1w = (unsigned)(size_t)&h1[quad * 4][colw];

    // ---- z prefetch pipeline (one tile ahead, registers only) ----
    float4 zn[2][2];   // [mb][half] raw fp32, valid on zlane only
    {
        const int base0 = blockIdx.x * 32;
        if (zlane && blockIdx.x < NTILE) {
#pragma unroll
            for (int mb = 0; mb < 2; ++mb) {
                const float* zp = z + (size_t)(base0 + mb * 16 + l15) * DIN + quad * 8;
                zn[mb][0] = *(const float4*)zp;
                zn[mb][1] = *(const float4*)(zp + 4);
            }
        }
    }

    __syncthreads();   // w1l visible to all waves

    int p = 0;
    for (int tile = blockIdx.x; tile < NTILE; tile += NWG, p ^= 1) {
        const int base = tile * 32;
        if (tid < 32) seg_sm[p][tid] = (int)seg[base + tid];

        float4 zc[2][2];
#pragma unroll
        for (int mb = 0; mb < 2; ++mb) { zc[mb][0] = zn[mb][0]; zc[mb][1] = zn[mb][1]; }
        const int ntile = tile + NWG;
        if (zlane && ntile < NTILE) {
            const int nb = ntile * 32;
#pragma unroll
            for (int mb = 0; mb < 2; ++mb) {
                const float* zp = z + (size_t)(nb + mb * 16 + l15) * DIN + quad * 8;
                zn[mb][0] = *(const float4*)zp;
                zn[mb][1] = *(const float4*)(zp + 4);
            }
        }

        // ---------------- layer 1 (K=16 padded to 32; bias in k=16 lane) ----
        bf16x8 w1f[4];
#pragma unroll
        for (int t = 0; t < 4; ++t)
            w1f[t] = ldb8(&w1l[((wave * 4 + t) * 16 + l15) * 32 + quad * 8]);

        f32x4 a1[2][4];
#pragma unroll
        for (int mb = 0; mb < 2; ++mb) {
            bf16x8 af;
            if (zlane) {
                u32x4 u;
                u[0] = cvtpk(zc[mb][0].x, zc[mb][0].y);
                u[1] = cvtpk(zc[mb][0].z, zc[mb][0].w);
                u[2] = cvtpk(zc[mb][1].x, zc[mb][1].y);
                u[3] = cvtpk(zc[mb][1].z, zc[mb][1].w);
                af = __builtin_bit_cast(bf16x8, u);
            } else {
                u32x4 u = {(quad == 2) ? 0x3F80u : 0u, 0u, 0u, 0u};   // bias lane
                af = __builtin_bit_cast(bf16x8, u);
            }
            const f32x4 zero = {0.f, 0.f, 0.f, 0.f};
#pragma unroll
            for (int t = 0; t < 4; ++t) a1[mb][t] = mfma16(af, w1f[t], zero);
        }

        // LN1 stats (row-pair packed; bias inside MFMA)
#pragma unroll
        for (int mb = 0; mb < 2; ++mb)
#pragma unroll
            for (int rp = 0; rp < 2; ++rp) {
                f32x2 sv = zero2, qv = zero2;
#pragma unroll
                for (int t = 0; t < 4; ++t) {
                    f32x2 y = rp ? hihalf(a1[mb][t]) : lohalf(a1[mb][t]);
                    sv = pkadd(sv, y);
                    qv = pkfma(y, y, qv);
                }
                float sa = rsum16(sv[0]), sb = rsum16(sv[1]);
                float qa = rsum16(qv[0]), qb = rsum16(qv[1]);
                if (l15 == 0) {
                    f32x2 s2 = {sa, sb};
                    f32x2 q2 = {qa, qb};
                    *(f32x2*)&part2[p][mb][quad * 2 + rp][wave * 2]     = s2;
                    *(f32x2*)&part2[p][mb][quad * 2 + rp][8 + wave * 2] = q2;
                }
            }
        __syncthreads();   // B1: stats visible; prior-iter h1 readers done

        // LN1 apply + ReLU + bf16 store (packed cvt + paired b16/b16_hi stores)
#pragma unroll
        for (int mb = 0; mb < 2; ++mb)
#pragma unroll
            for (int rp = 0; rp < 2; ++rp) {
                const float* pr = &part2[p][mb][quad * 2 + rp][0];
                f32x4 sa4 = *(const f32x4*)pr;
                f32x4 sb4 = *(const f32x4*)(pr + 4);
                f32x4 qa4 = *(const f32x4*)(pr + 8);
                f32x4 qb4 = *(const f32x4*)(pr + 12);
                f32x2 st2 = pkadd(pkadd(lohalf(sa4), hihalf(sa4)),
                                  pkadd(lohalf(sb4), hihalf(sb4)));
                f32x2 qt2 = pkadd(pkadd(lohalf(qa4), hihalf(qa4)),
                                  pkadd(lohalf(qb4), hihalf(qb4)));
                float m0 = st2[0] * (1.f / 256.f), m1 = st2[1] * (1.f / 256.f);
                float v0 = fmaf(qt2[0], 1.f / 256.f, -(m0 * m0));
                float v1 = fmaf(qt2[1], 1.f / 256.f, -(m1 * m1));
                float r0 = rsqrtf(fmaxf(v0, 0.f) + 1e-5f);
                float r1 = rsqrtf(fmaxf(v1, 0.f) + 1e-5f);
                f32x2 rs2 = {r0, r1};
                f32x2 mn2 = {-m0, -m1};
#pragma unroll
                for (int t = 0; t < 4; ++t) {
                    f32x2 A2 = pkmul(rs2, gd1[t]);
                    f32x2 C2 = pkfma(mn2, A2, ed1[t]);
                    f32x2 y  = rp ? hihalf(a1[mb][t]) : lohalf(a1[mb][t]);
                    f32x2 h2 = relu2(pkfma(y, A2, C2));
                    unsigned pkv  = cvtpk(h2[0], h2[1]);
                    unsigned addr = h1w + (unsigned)(mb * 8448 + rp * 1056 + t * 32);
                    asm volatile("ds_write_b16 %0, %1\n\t"
                                 "ds_write_b16_d16_hi %0, %1 offset:528"
                                 :: "v"(addr), "v"(pkv));
                }
            }
        __syncthreads();   // B2: h1 ready

        // ---------------- layer 2 ----------------
        f32x4 a2[2][4];
#pragma unroll
        for (int mb = 0; mb < 2; ++mb) {
            const f32x4 zero = {0.f, 0.f, 0.f, 0.f};
#pragma unroll
            for (int t = 0; t < 4; ++t) a2[mb][t] = zero;
#pragma unroll
            for (int ks = 0; ks < 8; ++ks) {
                bf16x8 af = ldb8(&h1[mb * 16 + l15][ks * 32 + quad * 8]);
#pragma unroll
                for (int t = 0; t < 4; ++t) a2[mb][t] = mfma16(af, bw2[t][ks], a2[mb][t]);
            }
        }
        // LN2 stats (y = a2 + b2, packed)
#pragma unroll
        for (int mb = 0; mb < 2; ++mb)
#pragma unroll
            for (int rp = 0; rp < 2; ++rp) {
                f32x2 sv = zero2, qv = zero2;
#pragma unroll
                for (int t = 0; t < 4; ++t) {
                    f32x2 y = pkadd(rp ? hihalf(a2[mb][t]) : lohalf(a2[mb][t]), bd2[t]);
                    sv = pkadd(sv, y);
                    qv = pkfma(y, y, qv);
                }
                float sa = rsum16(sv[0]), sb = rsum16(sv[1]);
                float qa = rsum16(qv[0]), qb = rsum16(qv[1]);
                if (l15 == 0) {
                    f32x2 s2 = {sa, sb};
                    f32x2 q2 = {qa, qb};
                    *(f32x2*)&part2[p][mb][quad * 2 + rp][wave * 2]     = s2;
                    *(f32x2*)&part2[p][mb][quad * 2 + rp][8 + wave * 2] = q2;
                }
            }
        __syncthreads();   // B3: layer-2 stats visible

        // LN2 apply + ReLU, written back into a2 for pooling
#pragma unroll
        for (int mb = 0; mb < 2; ++mb)
#pragma unroll
            for (int rp = 0; rp < 2; ++rp) {
                const float* pr = &part2[p][mb][quad * 2 + rp][0];
                f32x4 sa4 = *(const f32x4*)pr;
                f32x4 sb4 = *(const f32x4*)(pr + 4);
                f32x4 qa4 = *(const f32x4*)(pr + 8);
                f32x4 qb4 = *(const f32x4*)(pr + 12);
                f32x2 st2 = pkadd(pkadd(lohalf(sa4), hihalf(sa4)),
                                  pkadd(lohalf(sb4), hihalf(sb4)));
                f32x2 qt2 = pkadd(pkadd(lohalf(qa4), hihalf(qa4)),
                                  pkadd(lohalf(qb4), hihalf(qb4)));
                float m0 = st2[0] * (1.f / 256.f), m1 = st2[1] * (1.f / 256.f);
                float v0 = fmaf(qt2[0], 1.f / 256.f, -(m0 * m0));
                float v1 = fmaf(qt2[1], 1.f / 256.f, -(m1 * m1));
                float r0 = rsqrtf(fmaxf(v0, 0.f) + 1e-5f);
                float r1 = rsqrtf(fmaxf(v1, 0.f) + 1e-5f);
                f32x2 rs2 = {r0, r1};
                f32x2 mn2 = {-m0, -m1};
#pragma unroll
                for (int t = 0; t < 4; ++t) {
                    f32x2 A2 = pkmul(rs2, gd2[t]);
                    f32x2 C2 = pkfma(mn2, A2, ed2[t]);
                    f32x2 y  = pkadd(rp ? hihalf(a2[mb][t]) : lohalf(a2[mb][t]), bd2[t]);
                    f32x2 h2 = relu2(pkfma(y, A2, C2));
                    a2[mb][t][rp * 2]     = h2[0];
                    a2[mb][t][rp * 2 + 1] = h2[1];
                }
            }

        // ---------------- ragged segment-sum of h2 (fp32) ----------------
        const int s0  = seg_sm[p][0];
        const int s31 = seg_sm[p][31];
        if (s0 == s31) {   // tile entirely inside one segment (~94%)
#pragma unroll
            for (int t = 0; t < 4; ++t) {
                float cs = a2[0][t][0] + a2[0][t][1] + a2[0][t][2] + a2[0][t][3]
                         + a2[1][t][0] + a2[1][t][1] + a2[1][t][2] + a2[1][t][3];
                cs += __shfl_xor(cs, 16, 64);
                cs += __shfl_xor(cs, 32, 64);
                if (quad == 0)
                    atomicAdd(&sums_h[s0 * HDIM + colw + t * 16], cs);
            }
        } else {           // exactly 2 segments (min count 100 > 32)
            const int* sgp = &seg_sm[p][0];
            float m0v[4], m1v[4];
#pragma unroll
            for (int r = 0; r < 4; ++r) {
                m0v[r] = (sgp[quad * 4 + r]      == s0) ? 1.f : 0.f;
                m1v[r] = (sgp[16 + quad * 4 + r] == s0) ? 1.f : 0.f;
            }
#pragma unroll
            for (int t = 0; t < 4; ++t) {
                float cs = 0.f, ca = 0.f;
#pragma unroll
                for (int r = 0; r < 4; ++r) {
                    cs += a2[0][t][r] + a2[1][t][r];
                    ca = fmaf(a2[0][t][r], m0v[r], ca);
                    ca = fmaf(a2[1][t][r], m1v[r], ca);
                }
                cs += __shfl_xor(cs, 16, 64);
                cs += __shfl_xor(cs, 32, 64);
                ca += __shfl_xor(ca, 16, 64);
                ca += __shfl_xor(ca, 32, 64);
                if (quad == 0) {
                    atomicAdd(&sums_h[s0  * HDIM + colw + t * 16], ca);
                    atomicAdd(&sums_h[s31 * HDIM + colw + t * 16], cs - ca);
                }
            }
        }
    }
}

// ---------------------------------------------------------------------------
// emb[b] = (sums_h[b] @ W3) / count_b + b3
// ---------------------------------------------------------------------------
__global__ __launch_bounds__(128) void emb_gemm(const float* __restrict__ sums_h,
                                                const float* __restrict__ W3,
                                                const float* __restrict__ b3,
                                                const int* __restrict__ counts,
                                                float* __restrict__ emb) {
    const int b = blockIdx.x;
    const int o = threadIdx.x;
    const float* sh = sums_h + b * HDIM;
    float acc = 0.f;
#pragma unroll 8
    for (int k = 0; k < HDIM; ++k) acc = fmaf(sh[k], W3[k * DOUT + o], acc);
    emb[b * DOUT + o] = acc / (float)counts[b] + b3[o];
}

// ---------------------------------------------------------------------------
// out[n] = emb[seg[n]] ; unit-stride float4 per thread, nontemporal stores
// ---------------------------------------------------------------------------
__global__ __launch_bounds__(256) void broadcast_out(const float* __restrict__ emb,
                                                     const unsigned short* __restrict__ seg,
                                                     float* __restrict__ out) {
    const int idx = blockIdx.x * 256 + threadIdx.x;   // one float4; N*DOUT/4 total
    const int n = idx >> 5, c = idx & 31;
    const int s = seg[n];
    f32x4 v = ((const f32x4*)emb)[s * 32 + c];
    __builtin_nontemporal_store(v, (f32x4*)out + idx);
}

// ---------------------------------------------------------------------------
extern "C" void kernel_launch(void* const* d_in, const int* in_sizes, int n_in,
                              void* d_out, int out_size, void* d_ws, size_t ws_size,
                              hipStream_t stream) {
    const float* z   = (const float*)d_in[0];
    const float* W1  = (const float*)d_in[1];
    const float* b1  = (const float*)d_in[2];
    const float* g1  = (const float*)d_in[3];
    const float* be1 = (const float*)d_in[4];
    const float* W2  = (const float*)d_in[5];
    const float* b2  = (const float*)d_in[6];
    const float* g2  = (const float*)d_in[7];
    const float* be2 = (const float*)d_in[8];
    const float* W3  = (const float*)d_in[9];
    const float* b3  = (const float*)d_in[10];
    const int* counts = (const int*)d_in[11];
    float* out = (float*)d_out;

    char* ws = (char*)d_ws;
    float*          sums_h  = (float*)(ws);                     // 2,048,000 B
    float*          emb     = (float*)(ws + 2048000);           // 1,024,000 B
    int*            offsets = (int*)  (ws + 3072000);           //     8,016 B
    unsigned short* seg     = (unsigned short*)(ws + 3080016);  // 2,000,000 B
    unsigned short* w1t     = (unsigned short*)(ws + 5080016);  //    16,384 B
    unsigned short* w2t     = (unsigned short*)(ws + 5096400);  //   131,072 B

    hipMemsetAsync(sums_h, 0, (size_t)BSEG * HDIM * sizeof(float), stream);
    scan_counts<<<1, 1024, 0, stream>>>(counts, offsets);
    fill_seg<<<BSEG, 256, 0, stream>>>(offsets, seg);
    prep_weights<<<(HDIM * 32 + HDIM * HDIM) / 256, 256, 0, stream>>>(W1, b1, W2, w1t, w2t);
    fused_phi_pool<<<NWG, 256, 0, stream>>>(z, w1t, w2t,
                                            g1, be1, b2, g2, be2,
                                            seg, sums_h);
    emb_gemm<<<BSEG, 128, 0, stream>>>(sums_h, W3, b3, counts, emb);
    broadcast_out<<<NPTS * DOUT / 4 / 256, 256, 0, stream>>>(emb, seg, out);
}